// Round 4
// baseline (232.336 us; speedup 1.0000x reference)
//
#include <hip/hip_runtime.h>

#define NUM_INST 64
#define BLOCK 256
#define NWAVES 4
#define GRID 3125            // 3125 * 256 * 5 == 4,000,000 exactly (no tail in fast path)
#define KPT 5
#define NSLOT 72             // swizzled float4 slot index max = 63+7 = 70; pad to 72
#define SWZ(s) ((s) + ((s) >> 3))  // 64 slots -> 32 bank-classes x2 => <=2-way (free)

__global__ __launch_bounds__(BLOCK) void vsl_main(const float4* __restrict__ rows,
                                                  const int* __restrict__ labels,
                                                  float* __restrict__ gacc, int n) {
    __shared__ float4 Pbuf[NWAVES][NSLOT];          // first 4 dims of each lane's element
    __shared__ float4 Qbuf[NWAVES][NSLOT];          // last 4 dims
    __shared__ float red[NWAVES][NUM_INST * 10];    // per-wave flush totals

    const int tid = threadIdx.x;
    const int w = tid >> 6;
    const int lane = tid & 63;
    float4* P = Pbuf[w];
    float4* Q = Qbuf[w];

    // lane d owns instance d: register accumulators
    float s0 = 0, s1 = 0, s2 = 0, s3 = 0, s4 = 0, s5 = 0, s6 = 0, s7 = 0;
    float ssq = 0, cntf = 0;

    auto route = [&](float4 a, float4 b, int lbl, unsigned long long bv) {
        // publish: 16B-stride swizzled slots -> conflict-free b128 writes
        P[SWZ(lane)] = a;
        Q[SWZ(lane)] = b;
        // 6 ballots on label bits -> mask of source lanes whose label == my lane id
        unsigned long long m = bv;
#pragma unroll
        for (int bp = 0; bp < 6; ++bp) {
            const unsigned long long bb = __ballot((lbl >> bp) & 1);
            m &= ((lane >> bp) & 1) ? bb : ~bb;
        }
        cntf += (float)__popcll(m);  // exact integer counts, no atomics
        // gather: per while-iter all active lanes read DISTINCT slots (masks are
        // disjoint); swizzle keeps them <=2-way per bank -> ~free
        while (m) {
            const int s = (int)__builtin_ctzll(m);
            m &= m - 1;
            const float4 p = P[SWZ(s)];
            const float4 q = Q[SWZ(s)];
            s0 += p.x; s1 += p.y; s2 += p.z; s3 += p.w;
            s4 += q.x; s5 += q.y; s6 += q.z; s7 += q.w;
            ssq += p.x * p.x + p.y * p.y + p.z * p.z + p.w * p.w +
                   q.x * q.x + q.y * q.y + q.z * q.z + q.w * q.w;
        }
    };

    const int S = GRID * BLOCK;
    const int base = blockIdx.x * BLOCK + tid;

    if (n == S * KPT) {
        // fast path: exactly KPT elements per thread, no validity handling at all
        int lbl = labels[base];
        float4 a = rows[2 * base];
        float4 b = rows[2 * base + 1];
#pragma unroll
        for (int k = 0; k < KPT; ++k) {
            int nlbl = 0;
            float4 na = make_float4(0, 0, 0, 0), nb = make_float4(0, 0, 0, 0);
            if (k + 1 < KPT) {  // depth-1 prefetch of next element
                const int j = base + (k + 1) * S;
                nlbl = labels[j];
                na = rows[2 * j];
                nb = rows[2 * j + 1];
            }
            route(a, b, lbl, ~0ull);
            lbl = nlbl; a = na; b = nb;
        }
    } else {
        // generic fallback: uniform-exit ballot loop
        for (int i = base;; i += S) {
            const bool valid = (i < n);
            const unsigned long long bv = __ballot(valid);
            if (!bv) break;
            int lbl = 0;
            float4 a = make_float4(0, 0, 0, 0), b = make_float4(0, 0, 0, 0);
            if (valid) {
                lbl = labels[i];
                a = rows[2 * i];
                b = rows[2 * i + 1];
            }
            route(a, b, lbl, bv);
        }
    }

    // flush per-wave totals, then cross-wave reduce + one global atomic per stat
    float* fb = &red[w][lane * 10];
    fb[0] = s0; fb[1] = s1; fb[2] = s2; fb[3] = s3;
    fb[4] = s4; fb[5] = s5; fb[6] = s6; fb[7] = s7;
    fb[8] = ssq; fb[9] = cntf;
    __syncthreads();

    for (int j = tid; j < NUM_INST * 10; j += BLOCK) {
        float v = 0;
#pragma unroll
        for (int ww = 0; ww < NWAVES; ++ww) v += red[ww][j];
        atomicAdd(&gacc[j], v);
    }
}

__global__ __launch_bounds__(64) void vsl_final(const float* __restrict__ gacc,
                                                float* __restrict__ out) {
    const int s = threadIdx.x;  // one thread per instance, 1 wave
    float val = 0.0f;
    const float* base = &gacc[s * 10];
    const float cnt = base[9];
    if (s != 0 && cnt > 0.0f) {
        const float ss = base[8];
        float m2 = 0.0f;
#pragma unroll
        for (int d = 0; d < 8; ++d) {
            const float sd = base[d];
            m2 += sd * sd;
        }
        val = (ss - m2 / cnt) / (cnt * 8.0f);
    }
#pragma unroll
    for (int off = 32; off > 0; off >>= 1) val += __shfl_down(val, off, 64);
    if (s == 0) out[0] = val;
}

extern "C" void kernel_launch(void* const* d_in, const int* in_sizes, int n_in,
                              void* d_out, int out_size, void* d_ws, size_t ws_size,
                              hipStream_t stream) {
    const float* variances = (const float*)d_in[0];  // [N, 8] fp32
    const int* labels = (const int*)d_in[1];         // [N] int32
    const int n = in_sizes[1];                       // N
    float* gacc = (float*)d_ws;                      // 640 floats of scratch

    hipMemsetAsync(d_ws, 0, NUM_INST * 10 * sizeof(float), stream);
    vsl_main<<<GRID, BLOCK, 0, stream>>>((const float4*)variances, labels, gacc, n);
    vsl_final<<<1, 64, 0, stream>>>(gacc, (float*)d_out);
}

// Round 5
// 225.549 us; speedup vs baseline: 1.0301x; 1.0301x over previous
//
#include <hip/hip_runtime.h>

#define NUM_INST 64
#define BLOCK 256
#define NWAVES 4
#define GRID 2048
#define CAP 5   // slots per label per wave; rank>=CAP overflows to global atomics (Poisson tail ~1e-3)

__global__ __launch_bounds__(BLOCK) void vsl_main(const float4* __restrict__ rows,
                                                  const int* __restrict__ labels,
                                                  float* __restrict__ gacc, int n) {
    // per-wave private slots, layout [rank][label]: slot = 2 consecutive float4s.
    // For fixed rank, lanes (=labels) are 32B apart -> <=2-way banks (free).
    __shared__ float4 buf[NWAVES][CAP * NUM_INST * 2];  // 40 KB total
    const int tid = threadIdx.x;
    const int w = tid >> 6;
    const int lane = tid & 63;
    float4* B = buf[w];

    // lane d owns instance d
    float s0 = 0, s1 = 0, s2 = 0, s3 = 0, s4 = 0, s5 = 0, s6 = 0, s7 = 0;
    float ssq = 0, cntf = 0;
    const unsigned long long below = (lane == 0) ? 0ull : (~0ull >> (64 - lane));
    const int S = GRID * BLOCK;

    for (int i = blockIdx.x * BLOCK + tid;; i += S) {
        const bool valid = (i < n);
        const unsigned long long bv = __ballot(valid);
        if (!bv) break;  // wave-uniform exit

        int lbl = 0;
        float4 a = make_float4(0, 0, 0, 0), b = make_float4(0, 0, 0, 0);
        if (valid) {
            lbl = labels[i];
            a = rows[2 * i];
            b = rows[2 * i + 1];
        }

        // 6 ballots -> two masks: Md = sources whose label == my LANE id (dest view),
        //                         Ms = sources whose label == my LABEL (source view)
        unsigned long long Md = bv, Ms = bv;
#pragma unroll
        for (int bp = 0; bp < 6; ++bp) {
            const unsigned long long bb = __ballot((lbl >> bp) & 1);
            Md &= ((lane >> bp) & 1) ? bb : ~bb;
            Ms &= ((lbl >> bp) & 1) ? bb : ~bb;
        }
        const int rank = (int)__popcll(Ms & below);  // my index among same-label lanes
        const int cnt = (int)__popcll(Md);           // how many sources target my label

        if (valid) {
            if (rank < CAP) {
                float4* sp = &B[(rank * NUM_INST + lbl) * 2];
                sp[0] = a;
                sp[1] = b;
            } else {  // rare overflow: contribute directly (exact; dest caps its count)
                float* g = &gacc[lbl * 10];
                atomicAdd(g + 0, a.x); atomicAdd(g + 1, a.y);
                atomicAdd(g + 2, a.z); atomicAdd(g + 3, a.w);
                atomicAdd(g + 4, b.x); atomicAdd(g + 5, b.y);
                atomicAdd(g + 6, b.z); atomicAdd(g + 7, b.w);
                atomicAdd(g + 8, a.x * a.x + a.y * a.y + a.z * a.z + a.w * a.w +
                                 b.x * b.x + b.y * b.y + b.z * b.z + b.w * b.w);
                atomicAdd(g + 9, 1.0f);
            }
        }

        // publish must land before gather reads (same wave, DS in-order; stop reordering)
        asm volatile("s_waitcnt lgkmcnt(0)" ::: "memory");

        // fixed-trip gather: issue ALL CAP slot-pairs unconditionally (stale slots are
        // harmless), one waitcnt, then exec-predicated accumulate. No divergent chain.
        float4 P[CAP], Q[CAP];
#pragma unroll
        for (int r = 0; r < CAP; ++r) {
            const float4* sp = &B[(r * NUM_INST + lane) * 2];
            P[r] = sp[0];
            Q[r] = sp[1];
        }
        const int m = cnt < CAP ? cnt : CAP;
        cntf += (float)m;
#pragma unroll
        for (int r = 0; r < CAP; ++r) {
            if (r < m) {
                const float4 p = P[r], q = Q[r];
                s0 += p.x; s1 += p.y; s2 += p.z; s3 += p.w;
                s4 += q.x; s5 += q.y; s6 += q.z; s7 += q.w;
                ssq += p.x * p.x + p.y * p.y + p.z * p.z + p.w * p.w +
                       q.x * q.x + q.y * q.y + q.z * q.z + q.w * q.w;
            }
        }
    }

    // flush: reuse own wave's routing buffer for totals (2560 B < 10240 B region)
    float* rw = (float*)&buf[w][0];
    float* fb = &rw[lane * 10];
    fb[0] = s0; fb[1] = s1; fb[2] = s2; fb[3] = s3;
    fb[4] = s4; fb[5] = s5; fb[6] = s6; fb[7] = s7;
    fb[8] = ssq; fb[9] = cntf;
    __syncthreads();

    for (int j = tid; j < NUM_INST * 10; j += BLOCK) {
        float v = 0;
#pragma unroll
        for (int ww = 0; ww < NWAVES; ++ww) v += ((const float*)&buf[ww][0])[j];
        atomicAdd(&gacc[j], v);
    }
}

__global__ __launch_bounds__(64) void vsl_final(const float* __restrict__ gacc,
                                                float* __restrict__ out) {
    const int s = threadIdx.x;  // one thread per instance, 1 wave
    float val = 0.0f;
    const float* base = &gacc[s * 10];
    const float cnt = base[9];
    if (s != 0 && cnt > 0.0f) {
        const float ss = base[8];
        float m2 = 0.0f;
#pragma unroll
        for (int d = 0; d < 8; ++d) {
            const float sd = base[d];
            m2 += sd * sd;
        }
        val = (ss - m2 / cnt) / (cnt * 8.0f);
    }
#pragma unroll
    for (int off = 32; off > 0; off >>= 1) val += __shfl_down(val, off, 64);
    if (s == 0) out[0] = val;
}

extern "C" void kernel_launch(void* const* d_in, const int* in_sizes, int n_in,
                              void* d_out, int out_size, void* d_ws, size_t ws_size,
                              hipStream_t stream) {
    const float* variances = (const float*)d_in[0];  // [N, 8] fp32
    const int* labels = (const int*)d_in[1];         // [N] int32
    const int n = in_sizes[1];                       // N
    float* gacc = (float*)d_ws;                      // 640 floats of scratch

    hipMemsetAsync(d_ws, 0, NUM_INST * 10 * sizeof(float), stream);
    vsl_main<<<GRID, BLOCK, 0, stream>>>((const float4*)variances, labels, gacc, n);
    vsl_final<<<1, 64, 0, stream>>>(gacc, (float*)d_out);
}

// Round 6
// 212.477 us; speedup vs baseline: 1.0935x; 1.0615x over previous
//
#include <hip/hip_runtime.h>

#define NUM_INST 64
#define BLOCK 256
#define GRID 3125          // 3125 tiles/pass; N=4M -> 15625 tiles, 5 per block exactly
#define TILE_ROWS 256
#define SROW 9             // LDS row stride in dwords: gcd(9,32)=1 -> <=2-way banks
#define PSTRIDE 1088       // per-block partial: 64 inst * 16 feat + 64 counts
#define CHUNK 125          // K2: 3125 = 25 chunks * 125

typedef __attribute__((ext_vector_type(8))) short bf16x8;
typedef __attribute__((ext_vector_type(4))) float f32x4;

__global__ __launch_bounds__(BLOCK) void vsl_main(const float4* __restrict__ rows,
                                                  const int* __restrict__ labels,
                                                  float* __restrict__ partial,
                                                  int n, int ntiles) {
    __shared__ float S[TILE_ROWS * SROW];        // staged rows, 8 f32 + 1 pad dword
    __shared__ alignas(16) int Lab[TILE_ROWS];   // staged labels
    __shared__ float Cred[4][64];                // cross-wave count reduce

    const int tid = threadIdx.x;
    const int w = tid >> 6;          // wave id = m-tile id (instances 16w..16w+15)
    const int lane = tid & 63;
    const int g = lane >> 4;         // quad: k-subrange selector in MFMA frags
    const int nn = lane & 15;        // n (feature col) for B/D; m (local inst) for A
    const int f = nn & 7;            // source dim
    const bool hi = nn >= 8;         // cols 8..15 carry x^2
    const int inst = 16 * w + nn;    // A one-hot target for this lane

    f32x4 acc = {0.f, 0.f, 0.f, 0.f};
    float cntf = 0.f;

    for (int tile = blockIdx.x; tile < ntiles; tile += GRID) {
        // ---- stage: each wave loads its 64 rows + labels; count via ballots ----
        {
            const int r = 64 * w + lane;
            const int gr = tile * TILE_ROWS + r;
            const bool valid = gr < n;
            float4 a = make_float4(0, 0, 0, 0), b = make_float4(0, 0, 0, 0);
            int lb = 0;
            if (valid) { a = rows[2 * gr]; b = rows[2 * gr + 1]; lb = labels[gr]; }
            float* sp = &S[r * SROW];
            sp[0] = a.x; sp[1] = a.y; sp[2] = a.z; sp[3] = a.w;
            sp[4] = b.x; sp[5] = b.y; sp[6] = b.z; sp[7] = b.w;
            Lab[r] = lb;
            unsigned long long Md = __ballot(valid);   // exclude pad rows
#pragma unroll
            for (int bp = 0; bp < 6; ++bp) {
                const unsigned long long bb = __ballot((lb >> bp) & 1);
                Md &= ((lane >> bp) & 1) ? bb : ~bb;
            }
            cntf += (float)__popcll(Md);               // exact count, instance = lane
        }
        __syncthreads();

        // ---- compute: 8 k-batches of 32 rows; D[inst_local][feat] += onehot^T * [x|x^2]
#pragma unroll
        for (int kb = 0; kb < 8; ++kb) {
            const int rb = kb * 32 + 8 * g;            // first row of my frag k-range

            // B frag: elem j = feat(nn) of row rb+j (squared for cols>=8), bf16-packed
            const float* bp0 = &S[rb * SROW + f];
            union { int i[4]; bf16x8 v; } bf;
#pragma unroll
            for (int jp = 0; jp < 4; ++jp) {
                float v0 = bp0[(2 * jp) * SROW];
                float v1 = bp0[(2 * jp + 1) * SROW];
                if (hi) { v0 *= v0; v1 *= v1; }
                const unsigned u0 = __float_as_uint(v0) + 0x8000u;  // bf16 round
                const unsigned u1 = __float_as_uint(v1) + 0x8000u;
                bf.i[jp] = (int)__builtin_amdgcn_perm(u1, u0, 0x07060302u);
            }

            // A frag: elem j = (label[rb+j] == inst) ? 1.0bf16 : 0
            const int4 l0 = *(const int4*)&Lab[rb];
            const int4 l1 = *(const int4*)&Lab[rb + 4];
            union { int i[4]; bf16x8 v; } af;
            af.i[0] = ((l0.x == inst) ? 0x3F80 : 0) | ((l0.y == inst) ? 0x3F800000 : 0);
            af.i[1] = ((l0.z == inst) ? 0x3F80 : 0) | ((l0.w == inst) ? 0x3F800000 : 0);
            af.i[2] = ((l1.x == inst) ? 0x3F80 : 0) | ((l1.y == inst) ? 0x3F800000 : 0);
            af.i[3] = ((l1.z == inst) ? 0x3F80 : 0) | ((l1.w == inst) ? 0x3F800000 : 0);

            acc = __builtin_amdgcn_mfma_f32_16x16x32_bf16(af.v, bf.v, acc, 0, 0, 0);
        }
        __syncthreads();   // before next stage overwrites S/Lab
    }

    // ---- flush: per-block partials (no contended global atomics) ----
    Cred[w][lane] = cntf;
    __syncthreads();
    float* pb = &partial[(size_t)blockIdx.x * PSTRIDE];
    // D layout: col = lane&15 (feat), row = (lane>>4)*4 + reg (local inst)
#pragma unroll
    for (int r4 = 0; r4 < 4; ++r4) {
        const int instk = 16 * w + 4 * g + r4;
        pb[instk * 16 + nn] = acc[r4];
    }
    if (w == 0) {
        pb[1024 + lane] = Cred[0][lane] + Cred[1][lane] + Cred[2][lane] + Cred[3][lane];
    }
}

// K2: reduce GRID partial slices -> gacc[1088], 25 chunks of 125 slices each
__global__ __launch_bounds__(BLOCK) void vsl_reduce(const float* __restrict__ partial,
                                                    float* __restrict__ gacc) {
    const int id = blockIdx.x * BLOCK + threadIdx.x;
    if (id >= 25 * PSTRIDE) return;
    const int chunk = id / PSTRIDE;
    const int j = id - chunk * PSTRIDE;   // consecutive ids -> consecutive j: coalesced
    float s = 0.f;
    const float* p = &partial[(size_t)chunk * CHUNK * PSTRIDE + j];
#pragma unroll 5
    for (int q = 0; q < CHUNK; ++q) s += p[(size_t)q * PSTRIDE];
    atomicAdd(&gacc[j], s);               // 25 atomics/addr: trivial
}

__global__ __launch_bounds__(64) void vsl_final(const float* __restrict__ gacc,
                                                float* __restrict__ out) {
    const int i = threadIdx.x;            // one thread per instance
    float val = 0.f;
    const float cnt = gacc[1024 + i];
    if (i != 0 && cnt > 0.f) {
        const float* base = &gacc[i * 16];
        float ss = 0.f, m2 = 0.f;
#pragma unroll
        for (int d = 0; d < 8; ++d) {
            m2 += base[d] * base[d];      // ||sum||^2
            ss += base[8 + d];            // total sum of squares
        }
        val = (ss - m2 / cnt) / (cnt * 8.0f);
    }
#pragma unroll
    for (int off = 32; off > 0; off >>= 1) val += __shfl_down(val, off, 64);
    if (i == 0) out[0] = val;
}

extern "C" void kernel_launch(void* const* d_in, const int* in_sizes, int n_in,
                              void* d_out, int out_size, void* d_ws, size_t ws_size,
                              hipStream_t stream) {
    const float* variances = (const float*)d_in[0];  // [N, 8] fp32
    const int* labels = (const int*)d_in[1];         // [N] int32
    const int n = in_sizes[1];
    const int ntiles = (n + TILE_ROWS - 1) / TILE_ROWS;

    float* gacc = (float*)d_ws;                         // [1088] totals
    float* partial = (float*)((char*)d_ws + 8192);      // [GRID][1088] ~13.6 MB

    hipMemsetAsync(gacc, 0, PSTRIDE * sizeof(float), stream);
    vsl_main<<<GRID, BLOCK, 0, stream>>>((const float4*)variances, labels, partial, n, ntiles);
    vsl_reduce<<<(25 * PSTRIDE + BLOCK - 1) / BLOCK, BLOCK, 0, stream>>>(partial, gacc);
    vsl_final<<<1, 64, 0, stream>>>(gacc, (float*)d_out);
}

// Round 7
// 210.657 us; speedup vs baseline: 1.1029x; 1.0086x over previous
//
#include <hip/hip_runtime.h>

#define NUM_INST 64
#define BLOCK 256
#define GRID 3125          // N=4M -> 15625 tiles, exactly 5 per block
#define TILE_ROWS 256
#define PSTRIDE 1088       // per-block partial: 64 inst * 16 feat + 64 counts
#define CHUNK 125          // reduce: 3125 = 25 chunks * 125

typedef __attribute__((ext_vector_type(8))) short bf16x8;
typedef __attribute__((ext_vector_type(4))) float f32x4;

// MT[kb][col][g][j] shorts: kb*512 + col*32 + g*8 + j
//  - compute read (lane nn,g; kb): ds_read_b128 at kb*512 + nn*32 + g*8 -> 256 dense
//    dwords per instr (optimal 8 beats, no conflicts), zero VALU B-build.
//  - stage write (lane r=(kb,g,j); instr c): dword = kb*256+c*16+g*4+(j>>1) -> the 32
//    (kb,g,j>>1) combos hit 32 DISTINCT banks: 1 beat, conflict-free, imm offsets.
__global__ __launch_bounds__(BLOCK) void vsl_main(const float4* __restrict__ rows,
                                                  const int* __restrict__ labels,
                                                  float* __restrict__ partial,
                                                  int n, int ntiles) {
    __shared__ alignas(16) short MT[8 * 16 * 4 * 8];   // 8 KB
    __shared__ alignas(16) int Lab[TILE_ROWS];
    __shared__ float Cred[4][64];

    const int tid = threadIdx.x;
    const int w = tid >> 6;
    const int lane = tid & 63;
    const int g = lane >> 4;
    const int nn = lane & 15;
    const int inst = 16 * w + nn;

    const int r = tid;  // my staged row within the tile
    // stage-write base (shorts): kb*512 + g*8 + j
    const int wbase = ((r >> 5) * 512) + (((r >> 3) & 3) * 8) + (r & 7);

    f32x4 acc = {0.f, 0.f, 0.f, 0.f};
    float cntf = 0.f;

    int tile = blockIdx.x;
    // prefetch tile 0
    bool pv = false;
    float4 pa = make_float4(0, 0, 0, 0), pb = make_float4(0, 0, 0, 0);
    int plb = 0;
    if (tile < ntiles) {
        const int gr = tile * TILE_ROWS + r;
        pv = gr < n;
        if (pv) { pa = rows[2 * gr]; pb = rows[2 * gr + 1]; plb = labels[gr]; }
    }

    while (tile < ntiles) {
        // ---- counts (exact, via ballots; instance = lane id, per wave's 64 rows) ----
        unsigned long long Md = __ballot(pv);
#pragma unroll
        for (int bp = 0; bp < 6; ++bp) {
            const unsigned long long bb = __ballot((plb >> bp) & 1);
            Md &= ((lane >> bp) & 1) ? bb : ~bb;
        }
        cntf += (float)__popcll(Md);

        // ---- stage: bf16-convert my row (+ squares) into MFMA-ready MT ----
        float v[16];
        v[0] = pa.x; v[1] = pa.y; v[2] = pa.z; v[3] = pa.w;
        v[4] = pb.x; v[5] = pb.y; v[6] = pb.z; v[7] = pb.w;
#pragma unroll
        for (int c = 0; c < 8; ++c) v[8 + c] = v[c] * v[c];
#pragma unroll
        for (int c = 0; c < 16; ++c) {
            const unsigned u = __float_as_uint(v[c]) + 0x8000u;  // bf16 round
            MT[wbase + c * 32] = (short)(u >> 16);
        }
        Lab[r] = plb;  // invalid rows stage label 0 with zero data: harmless
        __syncthreads();

        // ---- prefetch next tile while this tile computes ----
        const int nt = tile + GRID;
        pv = false; pa = make_float4(0, 0, 0, 0); pb = make_float4(0, 0, 0, 0); plb = 0;
        if (nt < ntiles) {
            const int gr = nt * TILE_ROWS + r;
            pv = gr < n;
            if (pv) { pa = rows[2 * gr]; pb = rows[2 * gr + 1]; plb = labels[gr]; }
        }

        // ---- compute: 8 k-batches; D[inst][feat] += onehot^T * [x | x^2] ----
#pragma unroll
        for (int kb = 0; kb < 8; ++kb) {
            const int rb = kb * 32 + 8 * g;
            // B frag: one dense b128 read, already packed
            const bf16x8 bfrag = *(const bf16x8*)&MT[kb * 512 + nn * 32 + g * 8];
            // A frag: one-hot from labels (broadcast reads)
            const int4 l0 = *(const int4*)&Lab[rb];
            const int4 l1 = *(const int4*)&Lab[rb + 4];
            union { int i[4]; bf16x8 v; } af;
            af.i[0] = ((l0.x == inst) ? 0x3F80 : 0) | ((l0.y == inst) ? 0x3F800000 : 0);
            af.i[1] = ((l0.z == inst) ? 0x3F80 : 0) | ((l0.w == inst) ? 0x3F800000 : 0);
            af.i[2] = ((l1.x == inst) ? 0x3F80 : 0) | ((l1.y == inst) ? 0x3F800000 : 0);
            af.i[3] = ((l1.z == inst) ? 0x3F80 : 0) | ((l1.w == inst) ? 0x3F800000 : 0);
            acc = __builtin_amdgcn_mfma_f32_16x16x32_bf16(af.v, bfrag, acc, 0, 0, 0);
        }
        __syncthreads();  // before next stage overwrites MT/Lab
        tile = nt;
    }

    // ---- flush: per-block partials ----
    Cred[w][lane] = cntf;
    __syncthreads();
    float* pbk = &partial[(size_t)blockIdx.x * PSTRIDE];
    // D layout: col = lane&15 (feat), row = (lane>>4)*4 + reg (local inst)
#pragma unroll
    for (int r4 = 0; r4 < 4; ++r4) {
        const int instk = 16 * w + 4 * g + r4;
        pbk[instk * 16 + nn] = acc[r4];
    }
    if (w == 0) {
        pbk[1024 + lane] = Cred[0][lane] + Cred[1][lane] + Cred[2][lane] + Cred[3][lane];
    }
}

// reduce GRID partial slices -> gacc[1088]; lanes read consecutive j: coalesced
__global__ __launch_bounds__(BLOCK) void vsl_reduce(const float* __restrict__ partial,
                                                    float* __restrict__ gacc) {
    const int id = blockIdx.x * BLOCK + threadIdx.x;
    if (id >= 25 * PSTRIDE) return;
    const int chunk = id / PSTRIDE;
    const int j = id - chunk * PSTRIDE;
    float s = 0.f;
    const float* p = &partial[(size_t)chunk * CHUNK * PSTRIDE + j];
#pragma unroll 5
    for (int q = 0; q < CHUNK; ++q) s += p[(size_t)q * PSTRIDE];
    atomicAdd(&gacc[j], s);
}

__global__ __launch_bounds__(64) void vsl_final(const float* __restrict__ gacc,
                                                float* __restrict__ out) {
    const int i = threadIdx.x;
    float val = 0.f;
    const float cnt = gacc[1024 + i];
    if (i != 0 && cnt > 0.f) {
        const float* base = &gacc[i * 16];
        float ss = 0.f, m2 = 0.f;
#pragma unroll
        for (int d = 0; d < 8; ++d) {
            m2 += base[d] * base[d];   // ||sum||^2
            ss += base[8 + d];         // total sum of squares
        }
        val = (ss - m2 / cnt) / (cnt * 8.0f);
    }
#pragma unroll
    for (int off = 32; off > 0; off >>= 1) val += __shfl_down(val, off, 64);
    if (i == 0) out[0] = val;
}

extern "C" void kernel_launch(void* const* d_in, const int* in_sizes, int n_in,
                              void* d_out, int out_size, void* d_ws, size_t ws_size,
                              hipStream_t stream) {
    const float* variances = (const float*)d_in[0];  // [N, 8] fp32
    const int* labels = (const int*)d_in[1];         // [N] int32
    const int n = in_sizes[1];
    const int ntiles = (n + TILE_ROWS - 1) / TILE_ROWS;

    float* gacc = (float*)d_ws;                      // [1088] totals
    float* partial = (float*)((char*)d_ws + 8192);   // [GRID][1088] ~13.6 MB

    hipMemsetAsync(gacc, 0, PSTRIDE * sizeof(float), stream);
    vsl_main<<<GRID, BLOCK, 0, stream>>>((const float4*)variances, labels, partial, n, ntiles);
    vsl_reduce<<<(25 * PSTRIDE + BLOCK - 1) / BLOCK, BLOCK, 0, stream>>>(partial, gacc);
    vsl_final<<<1, 64, 0, stream>>>(gacc, (float*)d_out);
}